// Round 15
// baseline (743.215 us; speedup 1.0000x reference)
//
#include <hip/hip_runtime.h>

#define MDIM 8192
#define NDIM 16384
#define KDIM 4096

typedef int i32x4 __attribute__((ext_vector_type(4)));
typedef int i32x16 __attribute__((ext_vector_type(16)));
typedef float f32x4 __attribute__((ext_vector_type(4)));

__device__ __forceinline__ unsigned short f2bf(float f) {
  __bf16 h = (__bf16)f;
  return __builtin_bit_cast(unsigned short, h);
}

__device__ __forceinline__ void gload_lds16(const void* g, void* l) {
  __builtin_amdgcn_global_load_lds(
      (const __attribute__((address_space(1))) unsigned int*)g,
      (__attribute__((address_space(3))) unsigned int*)l, 16, 0, 0);
}

// ======== int8 ws layouts (ks-plane-major, 16B cells; LDS traffic contiguous)
// Ab: [panel(32 x 256rows)][kt64(64)][ks(4)][row(256)][16]
// Wb: [panel(64 x 256rows)][kt64(64)][ks(4)][row(256)][16]
// 128-row GEMM tiles address half-panels: p = tile>>1, h = tile&1 (+h*2048 B).

// ---------- pass 1a: dynamic per-row quantization A fp32 -> int8 ----------
__global__ __launch_bounds__(256) void cvt_a_q8(const float* __restrict__ a,
                                                signed char* __restrict__ o,
                                                float* __restrict__ sA) {
  const int row = blockIdx.x;  // 0..8191
  const int tid = threadIdx.x;
  float v[16];
  const float4* s4 = (const float4*)(a + (long long)row * KDIM + tid * 16);
#pragma unroll
  for (int i = 0; i < 4; ++i) {
    float4 f = s4[i];
    v[i * 4 + 0] = f.x; v[i * 4 + 1] = f.y;
    v[i * 4 + 2] = f.z; v[i * 4 + 3] = f.w;
  }
  float m = 0.f;
#pragma unroll
  for (int i = 0; i < 16; ++i) m = fmaxf(m, fabsf(v[i]));
#pragma unroll
  for (int off = 32; off; off >>= 1) m = fmaxf(m, __shfl_xor(m, off));
  __shared__ float red[4];
  if ((tid & 63) == 0) red[tid >> 6] = m;
  __syncthreads();
  m = fmaxf(fmaxf(red[0], red[1]), fmaxf(red[2], red[3]));
  const float inv = m > 0.f ? 127.f / m : 0.f;
  if (tid == 0) sA[row] = m * (1.f / 127.f);
  union { signed char c[16]; uint4 u; } p;
#pragma unroll
  for (int i = 0; i < 16; ++i)
    p.c[i] = (signed char)__float2int_rn(v[i] * inv);  // |v*inv| <= 127
  const int kt = tid >> 2, ks = tid & 3;
  *(uint4*)(o + ((((long long)(row >> 8) * 64 + kt) * 4 + ks) << 12) +
            ((row & 255) << 4)) = p.u;
}

// ---------- pass 1b: W int32 (int8 values, exact) -> int8 tile-panel --------
__global__ __launch_bounds__(256) void cvt_w_q8(const int* __restrict__ w,
                                                signed char* __restrict__ o) {
  const int nt = blockIdx.x >> 6;
  const int kt = blockIdx.x & 63;
  const int t = threadIdx.x;  // row (output channel within panel)
  const int* src = w + (long long)(nt * 256 + t) * KDIM + kt * 64;
  signed char* dst = o + (((long long)(nt * 64 + kt) * 4) << 12) + (t << 4);
#pragma unroll
  for (int ks = 0; ks < 4; ++ks) {
    union { signed char c[16]; uint4 u; } p;
#pragma unroll
    for (int i = 0; i < 4; ++i) {
      int4 x = *(const int4*)(src + ks * 16 + i * 4);
      p.c[i * 4 + 0] = (signed char)x.x; p.c[i * 4 + 1] = (signed char)x.y;
      p.c[i * 4 + 2] = (signed char)x.z; p.c[i * 4 + 3] = (signed char)x.w;
    }
    *(uint4*)(dst + (ks << 12)) = p.u;
  }
}

// ---------- pass 2: int8 GEMM, 128x128 tile, BK=64, 4 waves x (64x64),
// mfma_i32_32x32x32_i8, 3-slot ring (48 KiB -> 3 blocks/CU), vmcnt(4) ----
// Cross-block overlap is the lever: 3 independent blocks per CU (no shared
// barriers) let one block's MFMA phase run under another's LDS phase (m114).
// Slot (16KB): A [ks4][row128][16] at +0; B same at +8192.
// Frag reads: 32 lanes x 16B contiguous (conflict-free by layout).
__global__ __launch_bounds__(256, 3) void gemm_i8_v15(
    const signed char* __restrict__ Ab, const signed char* __restrict__ Wb,
    const float* __restrict__ sA, const float* __restrict__ sc,
    const float* __restrict__ bi, float* __restrict__ out) {
  __shared__ alignas(16) char sm[3 * 16384];
  const int tid = threadIdx.x;
  const int lane = tid & 63;
  const int wv = tid >> 6;   // 0..3
  const int l31 = lane & 31;
  const int l32 = lane >> 5;
  const int wr = wv >> 1;    // 0..1 -> rows wr*64
  const int wcn = wv & 1;    // 0..1 -> cols wcn*64
  // 2D XCD chunking: 8192 blocks; XCD c owns 16(m) x 64(n) tile rect, m-fast.
  const int c = blockIdx.x & 7;
  const int l = blockIdx.x >> 3;               // 0..1023
  const int mA = ((c & 3) << 4) + (l & 15);    // 0..63  (128-row tiles)
  const int nT = ((c >> 2) << 6) + (l >> 4);   // 0..127 (128-col tiles)
  const int bm = mA << 7;
  const int bn = nT << 7;

  // frag byte-offsets (slot-relative)
  int aO[2][2], bO[2][2];
#pragma unroll
  for (int kk = 0; kk < 2; ++kk) {
#pragma unroll
    for (int mb = 0; mb < 2; ++mb)
      aO[kk][mb] = (kk * 2 + l32) * 2048 + (wr * 64 + mb * 32 + l31) * 16;
#pragma unroll
    for (int nb = 0; nb < 2; ++nb)
      bO[kk][nb] = 8192 + (kk * 2 + l32) * 2048 + (wcn * 64 + nb * 32 + l31) * 16;
  }

  i32x16 acc[2][2] = {};

  // staging sources: panel p = tile>>1, half h = tile&1 (rows h*128..+128)
  // thread t covers (ks = 2i + t>>7, row = h*128 + (t&127)) for i = 0,1.
  const signed char* aSrc = Ab + ((long long)(mA >> 1) << 20) +
                            ((tid >> 7) << 12) + ((mA & 1) << 11) +
                            ((tid & 127) << 4);
  const signed char* bSrc = Wb + ((long long)(nT >> 1) << 20) +
                            ((tid >> 7) << 12) + ((nT & 1) << 11) +
                            ((tid & 127) << 4);
  const int t16 = tid << 4;

  char* bR = &sm[0];
  char* bN = &sm[16384];
  char* bS = &sm[32768];

  auto STAGE = [&](char* slot) {  // 4 gl_lds/thread = one 16KB K-tile (A+B)
    gload_lds16(aSrc, slot + t16);
    gload_lds16(aSrc + 8192, slot + 4096 + t16);
    gload_lds16(bSrc, slot + 8192 + t16);
    gload_lds16(bSrc + 8192, slot + 12288 + t16);
    aSrc += 16384;
    bSrc += 16384;
  };

  // prologue: tiles 0,1; vmcnt(4) retires tile 0 (tile 1's 4 stay in flight)
  STAGE(bR);
  STAGE(bN);
  asm volatile("s_waitcnt vmcnt(4)" ::: "memory");
  __builtin_amdgcn_s_barrier();

  for (int t = 0; t < 64; ++t) {
    if (t <= 61) STAGE(bS);  // tile t+2 -> slot of t-1 (freed at t-1 barrier)
    i32x4 aF[2][2], bF[2][2];
#pragma unroll
    for (int kk = 0; kk < 2; ++kk) {
#pragma unroll
      for (int mb = 0; mb < 2; ++mb) aF[kk][mb] = *(const i32x4*)(bR + aO[kk][mb]);
#pragma unroll
      for (int nb = 0; nb < 2; ++nb) bF[kk][nb] = *(const i32x4*)(bR + bO[kk][nb]);
    }
    __builtin_amdgcn_s_setprio(1);
#pragma unroll
    for (int kk = 0; kk < 2; ++kk)
#pragma unroll
      for (int mb = 0; mb < 2; ++mb)
#pragma unroll
        for (int nb = 0; nb < 2; ++nb)
          acc[mb][nb] = __builtin_amdgcn_mfma_i32_32x32x32_i8(
              aF[kk][mb], bF[kk][nb], acc[mb][nb], 0, 0, 0);
    __builtin_amdgcn_s_setprio(0);
    if (t <= 61) {
      asm volatile("s_waitcnt vmcnt(4)" ::: "memory");  // tile t+1 resident
    } else if (t == 62) {
      asm volatile("s_waitcnt vmcnt(0)" ::: "memory");  // tile 63 resident
    }
    if (t < 63) __builtin_amdgcn_s_barrier();
    char* tmp = bR; bR = bN; bN = bS; bS = tmp;
  }

  // epilogue: out = acc * sA[row]*scale[col] + bias[col]
  // 32x32 C/D layout: col = lane&31, row = (r&3) + 8*(r>>2) + 4*l32
  float sv[2], bv[2];
#pragma unroll
  for (int nb = 0; nb < 2; ++nb) {
    const int cc = bn + wcn * 64 + nb * 32 + l31;
    sv[nb] = sc[cc];
    bv[nb] = bi[cc];
  }
#pragma unroll
  for (int mb = 0; mb < 2; ++mb) {
    const int rb = bm + wr * 64 + mb * 32 + l32 * 4;
    float sa[16];
#pragma unroll
    for (int r = 0; r < 16; ++r) sa[r] = sA[rb + (r & 3) + 8 * (r >> 2)];
#pragma unroll
    for (int nb = 0; nb < 2; ++nb) {
      const int cc = bn + wcn * 64 + nb * 32 + l31;
#pragma unroll
      for (int r = 0; r < 16; ++r) {
        const long long row = rb + (r & 3) + 8 * (r >> 2);
        __builtin_nontemporal_store(
            (float)acc[mb][nb][r] * (sa[r] * sv[nb]) + bv[nb],
            out + row * NDIM + cc);
      }
    }
  }
}

// ---------- fallback: inline-convert reg-staged bf16 GEMM (if ws too small) ----
__global__ __launch_bounds__(256, 2) void gemm_inline(
    const float* __restrict__ A, const int* __restrict__ W,
    const float* __restrict__ sc, const float* __restrict__ bi,
    float* __restrict__ out) {
  typedef __bf16 bf16x8 __attribute__((ext_vector_type(8)));
  __shared__ unsigned short As[128 * 72];
  __shared__ unsigned short Bs[128 * 72];
  const int tid = threadIdx.x;
  const int lane = tid & 63;
  const int wv = tid >> 6;
  const int wg = (blockIdx.x & 7) * 1024 + (blockIdx.x >> 3);
  const int bm = (wg & 63) * 128;
  const int bn = (wg >> 6) * 128;
  const int wr = (wv >> 1) * 64;
  const int wc = (wv & 1) * 64;
  const int r16 = lane & 15;
  const int g4 = lane >> 4;

  f32x4 acc[4][4] = {};

  const int srow = tid >> 4;
  const int sc4 = (tid & 15) << 2;
  const float* aPtr = A + (long long)(bm + srow) * KDIM + sc4;
  const int* wPtr = W + (long long)(bn + srow) * KDIM + sc4;

  for (int kt = 0; kt < KDIM; kt += 64) {
    float4 av[8];
    int4 wv4[8];
#pragma unroll
    for (int j = 0; j < 8; ++j)
      av[j] = *(const float4*)(aPtr + (long long)j * 16 * KDIM + kt);
#pragma unroll
    for (int j = 0; j < 8; ++j)
      wv4[j] = *(const int4*)(wPtr + (long long)j * 16 * KDIM + kt);
    __syncthreads();
#pragma unroll
    for (int j = 0; j < 8; ++j) {
      ushort4 u;
      u.x = f2bf(av[j].x); u.y = f2bf(av[j].y);
      u.z = f2bf(av[j].z); u.w = f2bf(av[j].w);
      *(ushort4*)&As[(srow + j * 16) * 72 + sc4] = u;
    }
#pragma unroll
    for (int j = 0; j < 8; ++j) {
      ushort4 u;
      u.x = f2bf((float)wv4[j].x); u.y = f2bf((float)wv4[j].y);
      u.z = f2bf((float)wv4[j].z); u.w = f2bf((float)wv4[j].w);
      *(ushort4*)&Bs[(srow + j * 16) * 72 + sc4] = u;
    }
    __syncthreads();
#pragma unroll
    for (int ks = 0; ks < 2; ++ks) {
      bf16x8 aF[4], bF[4];
      const int kofs = ks * 32 + g4 * 8;
#pragma unroll
      for (int m2 = 0; m2 < 4; ++m2)
        aF[m2] = *(const bf16x8*)&As[(wr + m2 * 16 + r16) * 72 + kofs];
#pragma unroll
      for (int n2 = 0; n2 < 4; ++n2)
        bF[n2] = *(const bf16x8*)&Bs[(wc + n2 * 16 + r16) * 72 + kofs];
#pragma unroll
      for (int m2 = 0; m2 < 4; ++m2)
#pragma unroll
        for (int n2 = 0; n2 < 4; ++n2)
          acc[m2][n2] = __builtin_amdgcn_mfma_f32_16x16x32_bf16(
              aF[m2], bF[n2], acc[m2][n2], 0, 0, 0);
    }
  }

  float sv[4], bv[4];
#pragma unroll
  for (int n2 = 0; n2 < 4; ++n2) {
    const int c = bn + wc + n2 * 16 + r16;
    sv[n2] = sc[c];
    bv[n2] = bi[c];
  }
#pragma unroll
  for (int m2 = 0; m2 < 4; ++m2) {
    const int row0 = bm + wr + m2 * 16 + g4 * 4;
#pragma unroll
    for (int n2 = 0; n2 < 4; ++n2) {
      const int c = bn + wc + n2 * 16 + r16;
      float* op = out + (long long)row0 * NDIM + c;
#pragma unroll
      for (int r = 0; r < 4; ++r)
        op[(long long)r * NDIM] = acc[m2][n2][r] * sv[n2] + bv[n2];
    }
  }
}

extern "C" void kernel_launch(void* const* d_in, const int* in_sizes, int n_in,
                              void* d_out, int out_size, void* d_ws, size_t ws_size,
                              hipStream_t stream) {
  const float* A = (const float*)d_in[0];
  const int* W = (const int*)d_in[1];
  const float* sc = (const float*)d_in[2];
  const float* bi = (const float*)d_in[3];
  float* out = (float*)d_out;

  const size_t needA = (size_t)MDIM * KDIM;          // int8: 32 MB
  const size_t needW = (size_t)NDIM * KDIM;          // int8: 64 MB
  const size_t offS = needA + needW;                 // 96 MB
  const size_t need = offS + (size_t)MDIM * 4;       // + sA

  if (d_ws != nullptr && ws_size >= need) {
    signed char* Ab = (signed char*)d_ws;
    signed char* Wb = (signed char*)d_ws + needA;
    float* sA = (float*)((char*)d_ws + offS);
    cvt_a_q8<<<8192, 256, 0, stream>>>(A, Ab, sA);
    cvt_w_q8<<<4096, 256, 0, stream>>>(W, Wb);
    gemm_i8_v15<<<8192, 256, 0, stream>>>(Ab, Wb, sA, sc, bi, out);
  } else {
    gemm_inline<<<8192, 256, 0, stream>>>(A, W, sc, bi, out);
  }
}

// Round 16
// 733.889 us; speedup vs baseline: 1.0127x; 1.0127x over previous
//
#include <hip/hip_runtime.h>

#define MDIM 8192
#define NDIM 16384
#define KDIM 4096

typedef int i32x4 __attribute__((ext_vector_type(4)));
typedef int i32x16 __attribute__((ext_vector_type(16)));
typedef float f32x4 __attribute__((ext_vector_type(4)));

__device__ __forceinline__ unsigned short f2bf(float f) {
  __bf16 h = (__bf16)f;
  return __builtin_bit_cast(unsigned short, h);
}

// ======== int8 ws layouts (ks-plane-major, 16B cells) ======
// Ab: [mtile(32)][kt64(64)][ks(4)][row(256)][16]  -> 16KB per (mtile,kt)
// Wb: [ntile(64)][kt64(64)][ks(4)][row(256)][16]
// Every MFMA fragment = 32 lanes x 16B contiguous in ws -> perfectly
// coalesced global_load_dwordx4. sA: 8192 floats after Wb.

// ---------- pass 1a: dynamic per-row quantization A fp32 -> int8 ----------
__global__ __launch_bounds__(256) void cvt_a_q8(const float* __restrict__ a,
                                                signed char* __restrict__ o,
                                                float* __restrict__ sA) {
  const int row = blockIdx.x;  // 0..8191
  const int tid = threadIdx.x;
  float v[16];
  const float4* s4 = (const float4*)(a + (long long)row * KDIM + tid * 16);
#pragma unroll
  for (int i = 0; i < 4; ++i) {
    float4 f = s4[i];
    v[i * 4 + 0] = f.x; v[i * 4 + 1] = f.y;
    v[i * 4 + 2] = f.z; v[i * 4 + 3] = f.w;
  }
  float m = 0.f;
#pragma unroll
  for (int i = 0; i < 16; ++i) m = fmaxf(m, fabsf(v[i]));
#pragma unroll
  for (int off = 32; off; off >>= 1) m = fmaxf(m, __shfl_xor(m, off));
  __shared__ float red[4];
  if ((tid & 63) == 0) red[tid >> 6] = m;
  __syncthreads();
  m = fmaxf(fmaxf(red[0], red[1]), fmaxf(red[2], red[3]));
  const float inv = m > 0.f ? 127.f / m : 0.f;
  if (tid == 0) sA[row] = m * (1.f / 127.f);
  union { signed char c[16]; uint4 u; } p;
#pragma unroll
  for (int i = 0; i < 16; ++i)
    p.c[i] = (signed char)__float2int_rn(v[i] * inv);  // |v*inv| <= 127
  const int kt = tid >> 2, ks = tid & 3;
  *(uint4*)(o + ((((long long)(row >> 8) * 64 + kt) * 4 + ks) << 12) +
            ((row & 255) << 4)) = p.u;
}

// ---------- pass 1b: W int32 (int8 values, exact) -> int8 tile-panel --------
__global__ __launch_bounds__(256) void cvt_w_q8(const int* __restrict__ w,
                                                signed char* __restrict__ o) {
  const int nt = blockIdx.x >> 6;
  const int kt = blockIdx.x & 63;
  const int t = threadIdx.x;  // row (output channel within panel)
  const int* src = w + (long long)(nt * 256 + t) * KDIM + kt * 64;
  signed char* dst = o + (((long long)(nt * 64 + kt) * 4) << 12) + (t << 4);
#pragma unroll
  for (int ks = 0; ks < 4; ++ks) {
    union { signed char c[16]; uint4 u; } p;
#pragma unroll
    for (int i = 0; i < 4; ++i) {
      int4 x = *(const int4*)(src + ks * 16 + i * 4);
      p.c[i * 4 + 0] = (signed char)x.x; p.c[i * 4 + 1] = (signed char)x.y;
      p.c[i * 4 + 2] = (signed char)x.z; p.c[i * 4 + 3] = (signed char)x.w;
    }
    *(uint4*)(dst + (ks << 12)) = p.u;
  }
}

// ---------- pass 2: int8 GEMM, NO LDS — direct global->VGPR fragments ----
// 256x256 tile, BK=64, 8 waves x (128x64), mfma_i32_32x32x32_i8.
// ws is 96 MB (fits 256MB L3; FETCH measured 0.4GB = 97% cache-served), and
// the tile-panel layout makes every fragment a coalesced 32-lane x 16B
// global_load_dwordx4 — LDS staging was pure overhead (Common-mistake #7).
// Register double-buffer, 2-tile dependency distance (~2300 cyc >> L2 lat).
// No barriers, no inline asm: compiler inserts exact vmcnt waits.
__global__ __launch_bounds__(512, 1) void gemm_i8_v16(
    const signed char* __restrict__ Ab, const signed char* __restrict__ Wb,
    const float* __restrict__ sA, const float* __restrict__ sc,
    const float* __restrict__ bi, float* __restrict__ out) {
  const int tid = threadIdx.x;
  const int lane = tid & 63;
  const int wv = tid >> 6;
  const int l31 = lane & 31;
  const int l32 = lane >> 5;
  const int wr = wv >> 2;   // 0..1 -> rows wr*128
  const int wc = wv & 3;    // 0..3 -> cols wc*64
  // 2D XCD chunking (verified: low FETCH)
  const int c = blockIdx.x & 7;
  const int l = blockIdx.x >> 3;              // 0..255
  const int mA = ((c & 3) << 3) + (l & 7);    // 0..31
  const int nT = ((c >> 2) << 5) + (l >> 3);  // 0..63
  const int bm = mA << 8;
  const int bn = nT << 8;

  // per-lane fragment pointers into ws (advance 16KB per K-tile)
  const signed char* aP[2][4];
  const signed char* bP[2][2];
#pragma unroll
  for (int kk = 0; kk < 2; ++kk) {
#pragma unroll
    for (int mb = 0; mb < 4; ++mb)
      aP[kk][mb] = Ab + ((long long)mA << 20) + (kk * 2 + l32) * 4096 +
                   (wr * 128 + mb * 32 + l31) * 16;
#pragma unroll
    for (int nb = 0; nb < 2; ++nb)
      bP[kk][nb] = Wb + ((long long)nT << 20) + (kk * 2 + l32) * 4096 +
                   (wc * 64 + nb * 32 + l31) * 16;
  }

  i32x16 acc[4][2] = {};

  auto LOADG = [&](i32x4 (&aF)[2][4], i32x4 (&bF)[2][2]) {
#pragma unroll
    for (int kk = 0; kk < 2; ++kk) {
#pragma unroll
      for (int mb = 0; mb < 4; ++mb) aF[kk][mb] = *(const i32x4*)aP[kk][mb];
#pragma unroll
      for (int nb = 0; nb < 2; ++nb) bF[kk][nb] = *(const i32x4*)bP[kk][nb];
    }
  };
  auto ADV = [&]() {
#pragma unroll
    for (int kk = 0; kk < 2; ++kk) {
#pragma unroll
      for (int mb = 0; mb < 4; ++mb) aP[kk][mb] += 16384;
#pragma unroll
      for (int nb = 0; nb < 2; ++nb) bP[kk][nb] += 16384;
    }
  };
  auto MFMAS = [&](const i32x4 (&aF)[2][4], const i32x4 (&bF)[2][2]) {
#pragma unroll
    for (int kk = 0; kk < 2; ++kk)
#pragma unroll
      for (int mb = 0; mb < 4; ++mb)
#pragma unroll
        for (int nb = 0; nb < 2; ++nb)
          acc[mb][nb] = __builtin_amdgcn_mfma_i32_32x32x32_i8(
              aF[kk][mb], bF[kk][nb], acc[mb][nb], 0, 0, 0);
  };

  i32x4 aFa[2][4], bFa[2][2], aFb[2][4], bFb[2][2];

  LOADG(aFa, bFa);  // tile 0
  ADV();
  for (int i = 0; i < 31; ++i) {   // tiles 0..61
    LOADG(aFb, bFb);               // tile 2i+1
    ADV();
    MFMAS(aFa, bFa);               // tile 2i
    LOADG(aFa, bFa);               // tile 2i+2
    ADV();
    MFMAS(aFb, bFb);               // tile 2i+1
  }
  LOADG(aFb, bFb);                 // tile 63
  MFMAS(aFa, bFa);                 // tile 62
  MFMAS(aFb, bFb);                 // tile 63

  // epilogue: out = acc * sA[row]*scale[col] + bias[col]
  // 32x32 C/D layout: col = lane&31, row = (r&3) + 8*(r>>2) + 4*l32
  float sv[2], bv[2];
#pragma unroll
  for (int nb = 0; nb < 2; ++nb) {
    const int cc = bn + wc * 64 + nb * 32 + l31;
    sv[nb] = sc[cc];
    bv[nb] = bi[cc];
  }
#pragma unroll
  for (int mb = 0; mb < 4; ++mb) {
    const int rb = bm + wr * 128 + mb * 32 + l32 * 4;
    float sa[16];
#pragma unroll
    for (int r = 0; r < 16; ++r) sa[r] = sA[rb + (r & 3) + 8 * (r >> 2)];
#pragma unroll
    for (int nb = 0; nb < 2; ++nb) {
      const int cc = bn + wc * 64 + nb * 32 + l31;
#pragma unroll
      for (int r = 0; r < 16; ++r) {
        const long long row = rb + (r & 3) + 8 * (r >> 2);
        __builtin_nontemporal_store(
            (float)acc[mb][nb][r] * (sa[r] * sv[nb]) + bv[nb],
            out + row * NDIM + cc);
      }
    }
  }
}

// ---------- fallback: inline-convert reg-staged bf16 GEMM (if ws too small) ----
__global__ __launch_bounds__(256, 2) void gemm_inline(
    const float* __restrict__ A, const int* __restrict__ W,
    const float* __restrict__ sc, const float* __restrict__ bi,
    float* __restrict__ out) {
  typedef __bf16 bf16x8 __attribute__((ext_vector_type(8)));
  __shared__ unsigned short As[128 * 72];
  __shared__ unsigned short Bs[128 * 72];
  const int tid = threadIdx.x;
  const int lane = tid & 63;
  const int wv = tid >> 6;
  const int wg = (blockIdx.x & 7) * 1024 + (blockIdx.x >> 3);
  const int bm = (wg & 63) * 128;
  const int bn = (wg >> 6) * 128;
  const int wr = (wv >> 1) * 64;
  const int wc = (wv & 1) * 64;
  const int r16 = lane & 15;
  const int g4 = lane >> 4;

  f32x4 acc[4][4] = {};

  const int srow = tid >> 4;
  const int sc4 = (tid & 15) << 2;
  const float* aPtr = A + (long long)(bm + srow) * KDIM + sc4;
  const int* wPtr = W + (long long)(bn + srow) * KDIM + sc4;

  for (int kt = 0; kt < KDIM; kt += 64) {
    float4 av[8];
    int4 wv4[8];
#pragma unroll
    for (int j = 0; j < 8; ++j)
      av[j] = *(const float4*)(aPtr + (long long)j * 16 * KDIM + kt);
#pragma unroll
    for (int j = 0; j < 8; ++j)
      wv4[j] = *(const int4*)(wPtr + (long long)j * 16 * KDIM + kt);
    __syncthreads();
#pragma unroll
    for (int j = 0; j < 8; ++j) {
      ushort4 u;
      u.x = f2bf(av[j].x); u.y = f2bf(av[j].y);
      u.z = f2bf(av[j].z); u.w = f2bf(av[j].w);
      *(ushort4*)&As[(srow + j * 16) * 72 + sc4] = u;
    }
#pragma unroll
    for (int j = 0; j < 8; ++j) {
      ushort4 u;
      u.x = f2bf((float)wv4[j].x); u.y = f2bf((float)wv4[j].y);
      u.z = f2bf((float)wv4[j].z); u.w = f2bf((float)wv4[j].w);
      *(ushort4*)&Bs[(srow + j * 16) * 72 + sc4] = u;
    }
    __syncthreads();
#pragma unroll
    for (int ks = 0; ks < 2; ++ks) {
      bf16x8 aF[4], bF[4];
      const int kofs = ks * 32 + g4 * 8;
#pragma unroll
      for (int m2 = 0; m2 < 4; ++m2)
        aF[m2] = *(const bf16x8*)&As[(wr + m2 * 16 + r16) * 72 + kofs];
#pragma unroll
      for (int n2 = 0; n2 < 4; ++n2)
        bF[n2] = *(const bf16x8*)&Bs[(wc + n2 * 16 + r16) * 72 + kofs];
#pragma unroll
      for (int m2 = 0; m2 < 4; ++m2)
#pragma unroll
        for (int n2 = 0; n2 < 4; ++n2)
          acc[m2][n2] = __builtin_amdgcn_mfma_f32_16x16x32_bf16(
              aF[m2], bF[n2], acc[m2][n2], 0, 0, 0);
    }
  }

  float sv[4], bv[4];
#pragma unroll
  for (int n2 = 0; n2 < 4; ++n2) {
    const int c = bn + wc + n2 * 16 + r16;
    sv[n2] = sc[c];
    bv[n2] = bi[c];
  }
#pragma unroll
  for (int m2 = 0; m2 < 4; ++m2) {
    const int row0 = bm + wr + m2 * 16 + g4 * 4;
#pragma unroll
    for (int n2 = 0; n2 < 4; ++n2) {
      const int c = bn + wc + n2 * 16 + r16;
      float* op = out + (long long)row0 * NDIM + c;
#pragma unroll
      for (int r = 0; r < 4; ++r)
        op[(long long)r * NDIM] = acc[m2][n2][r] * sv[n2] + bv[n2];
    }
  }
}

extern "C" void kernel_launch(void* const* d_in, const int* in_sizes, int n_in,
                              void* d_out, int out_size, void* d_ws, size_t ws_size,
                              hipStream_t stream) {
  const float* A = (const float*)d_in[0];
  const int* W = (const int*)d_in[1];
  const float* sc = (const float*)d_in[2];
  const float* bi = (const float*)d_in[3];
  float* out = (float*)d_out;

  const size_t needA = (size_t)MDIM * KDIM;          // int8: 32 MB
  const size_t needW = (size_t)NDIM * KDIM;          // int8: 64 MB
  const size_t offS = needA + needW;                 // 96 MB
  const size_t need = offS + (size_t)MDIM * 4;       // + sA

  if (d_ws != nullptr && ws_size >= need) {
    signed char* Ab = (signed char*)d_ws;
    signed char* Wb = (signed char*)d_ws + needA;
    float* sA = (float*)((char*)d_ws + offS);
    cvt_a_q8<<<8192, 256, 0, stream>>>(A, Ab, sA);
    cvt_w_q8<<<4096, 256, 0, stream>>>(W, Wb);
    gemm_i8_v16<<<2048, 512, 0, stream>>>(Ab, Wb, sA, sc, bi, out);
  } else {
    gemm_inline<<<8192, 256, 0, stream>>>(A, W, sc, bi, out);
  }
}

// Round 17
// 692.549 us; speedup vs baseline: 1.0732x; 1.0597x over previous
//
#include <hip/hip_runtime.h>

#define MDIM 8192
#define NDIM 16384
#define KDIM 4096

typedef int i32x4 __attribute__((ext_vector_type(4)));
typedef int i32x16 __attribute__((ext_vector_type(16)));
typedef float f32x4 __attribute__((ext_vector_type(4)));

__device__ __forceinline__ unsigned short f2bf(float f) {
  __bf16 h = (__bf16)f;
  return __builtin_bit_cast(unsigned short, h);
}

__device__ __forceinline__ void gload_lds16(const void* g, void* l) {
  __builtin_amdgcn_global_load_lds(
      (const __attribute__((address_space(1))) unsigned int*)g,
      (__attribute__((address_space(3))) unsigned int*)l, 16, 0, 0);
}

// ======== int8 ws layouts (ks-plane-major, 16B cells) ======
// Ab: [mtile(32)][kt64(64)][ks(4)][row(256)][16]  -> 16KB per (mtile,kt)
// Wb: [ntile(64)][kt64(64)][ks(4)][row(256)][16]
// Every MFMA fragment = 32 lanes x 16B contiguous. sA: 8192 floats after Wb.

// ---------- pass 1a: dynamic per-row quantization A fp32 -> int8 ----------
__global__ __launch_bounds__(256) void cvt_a_q8(const float* __restrict__ a,
                                                signed char* __restrict__ o,
                                                float* __restrict__ sA) {
  const int row = blockIdx.x;  // 0..8191
  const int tid = threadIdx.x;
  float v[16];
  const float4* s4 = (const float4*)(a + (long long)row * KDIM + tid * 16);
#pragma unroll
  for (int i = 0; i < 4; ++i) {
    float4 f = s4[i];
    v[i * 4 + 0] = f.x; v[i * 4 + 1] = f.y;
    v[i * 4 + 2] = f.z; v[i * 4 + 3] = f.w;
  }
  float m = 0.f;
#pragma unroll
  for (int i = 0; i < 16; ++i) m = fmaxf(m, fabsf(v[i]));
#pragma unroll
  for (int off = 32; off; off >>= 1) m = fmaxf(m, __shfl_xor(m, off));
  __shared__ float red[4];
  if ((tid & 63) == 0) red[tid >> 6] = m;
  __syncthreads();
  m = fmaxf(fmaxf(red[0], red[1]), fmaxf(red[2], red[3]));
  const float inv = m > 0.f ? 127.f / m : 0.f;
  if (tid == 0) sA[row] = m * (1.f / 127.f);
  union { signed char c[16]; uint4 u; } p;
#pragma unroll
  for (int i = 0; i < 16; ++i)
    p.c[i] = (signed char)__float2int_rn(v[i] * inv);  // |v*inv| <= 127
  const int kt = tid >> 2, ks = tid & 3;
  *(uint4*)(o + ((((long long)(row >> 8) * 64 + kt) * 4 + ks) << 12) +
            ((row & 255) << 4)) = p.u;
}

// ---------- pass 1b: W int32 (int8 values, exact) -> int8 tile-panel --------
__global__ __launch_bounds__(256) void cvt_w_q8(const int* __restrict__ w,
                                                signed char* __restrict__ o) {
  const int nt = blockIdx.x >> 6;
  const int kt = blockIdx.x & 63;
  const int t = threadIdx.x;  // row (output channel within panel)
  const int* src = w + (long long)(nt * 256 + t) * KDIM + kt * 64;
  signed char* dst = o + (((long long)(nt * 64 + kt) * 4) << 12) + (t << 4);
#pragma unroll
  for (int ks = 0; ks < 4; ++ks) {
    union { signed char c[16]; uint4 u; } p;
#pragma unroll
    for (int i = 0; i < 4; ++i) {
      int4 x = *(const int4*)(src + ks * 16 + i * 4);
      p.c[i * 4 + 0] = (signed char)x.x; p.c[i * 4 + 1] = (signed char)x.y;
      p.c[i * 4 + 2] = (signed char)x.z; p.c[i * 4 + 3] = (signed char)x.w;
    }
    *(uint4*)(dst + (ks << 12)) = p.u;
  }
}

// ---------- pass 2: int8 GEMM, hybrid staging: A via LDS (4x reuse),
// B direct global->VGPR (2x reuse, L2/L3-served; v16 proved the path) ----
// 256x256 tile, BK=64, 8 waves x (128x64), mfma_i32_32x32x32_i8,
// A: 3-slot ring 48 KiB. Per iter t (program order of vmem):
//   [STAGE_A(t+2): 2 gl_lds] [LOADB(t+1): 4 global_load] [ds_read A(t)]
//   [MFMA(t) w/ B bank from t-1] [vmcnt(6)] [barrier]
// vmcnt(6) keeps exactly {stage(t+2), loadB(t+1)} -> A-stage(t+1) and
// loadB(t) retired (in-order) => tile t+1 fully resident after barrier.
// Tail: t=62 -> vmcnt(4); t=63 -> none. WAR: stage(t+2) -> slot of t-1,
// freed at t-1's barrier.
__global__ __launch_bounds__(512, 2) void gemm_i8_v17(
    const signed char* __restrict__ Ab, const signed char* __restrict__ Wb,
    const float* __restrict__ sA, const float* __restrict__ sc,
    const float* __restrict__ bi, float* __restrict__ out) {
  __shared__ alignas(16) char sm[3 * 16384];
  const int tid = threadIdx.x;
  const int lane = tid & 63;
  const int wv = tid >> 6;
  const int l31 = lane & 31;
  const int l32 = lane >> 5;
  const int wr = wv >> 2;   // 0..1 -> rows wr*128
  const int wc = wv & 3;    // 0..3 -> cols wc*64
  // 2D XCD chunking (verified: low FETCH)
  const int c = blockIdx.x & 7;
  const int l = blockIdx.x >> 3;              // 0..255
  const int mA = ((c & 3) << 3) + (l & 7);    // 0..31
  const int nT = ((c >> 2) << 5) + (l >> 3);  // 0..63
  const int bm = mA << 8;
  const int bn = nT << 8;

  // A frag LDS byte-offsets (slot-relative); 32 lanes x 16B contiguous
  int aO[2][4];
#pragma unroll
  for (int kk = 0; kk < 2; ++kk)
#pragma unroll
    for (int mb = 0; mb < 4; ++mb)
      aO[kk][mb] = (kk * 2 + l32) * 4096 + (wr * 128 + mb * 32 + l31) * 16;

  // B frag global pointers (advance 16KB per K-tile)
  const signed char* bP[2][2];
#pragma unroll
  for (int kk = 0; kk < 2; ++kk)
#pragma unroll
    for (int nb = 0; nb < 2; ++nb)
      bP[kk][nb] = Wb + ((long long)nT << 20) + (kk * 2 + l32) * 4096 +
                   (wc * 64 + nb * 32 + l31) * 16;

  i32x16 acc[4][2] = {};

  const signed char* aSt = Ab + ((long long)mA << 20) + (tid << 4);
  const int t16 = tid << 4;

  char* bR = &sm[0];
  char* bN = &sm[16384];
  char* bS = &sm[32768];

  auto STAGE_A = [&](char* slot) {  // 2 gl_lds/thread = one 16KB A K-tile
    gload_lds16(aSt, slot + t16);
    gload_lds16(aSt + 8192, slot + 8192 + t16);
    aSt += 16384;
  };
  auto LOADB = [&](i32x4 (&bF)[2][2]) {  // 4 coalesced global loads
#pragma unroll
    for (int kk = 0; kk < 2; ++kk)
#pragma unroll
      for (int nb = 0; nb < 2; ++nb) {
        bF[kk][nb] = *(const i32x4*)bP[kk][nb];
        bP[kk][nb] += 16384;
      }
  };

  i32x4 bFa[2][2], bFb[2][2];

  // prologue: A(0),A(1) staged; B(0) loaded; vmcnt(6) retires A(0)
  STAGE_A(bR);
  STAGE_A(bN);
  LOADB(bFa);
  asm volatile("s_waitcnt vmcnt(6)" ::: "memory");
  __builtin_amdgcn_s_barrier();

  auto TILE = [&](int t, i32x4 (&bCur)[2][2], i32x4 (&bNxt)[2][2]) {
    if (t <= 61) STAGE_A(bS);  // A(t+2) -> slot of t-1 (freed at t-1 barrier)
    if (t <= 62) LOADB(bNxt);  // B(t+1)
    i32x4 aF[2][4];
#pragma unroll
    for (int kk = 0; kk < 2; ++kk)
#pragma unroll
      for (int mb = 0; mb < 4; ++mb)
        aF[kk][mb] = *(const i32x4*)(bR + aO[kk][mb]);
    __builtin_amdgcn_s_setprio(1);
#pragma unroll
    for (int kk = 0; kk < 2; ++kk)
#pragma unroll
      for (int mb = 0; mb < 4; ++mb)
#pragma unroll
        for (int nb = 0; nb < 2; ++nb)
          acc[mb][nb] = __builtin_amdgcn_mfma_i32_32x32x32_i8(
              aF[kk][mb], bCur[kk][nb], acc[mb][nb], 0, 0, 0);
    __builtin_amdgcn_s_setprio(0);
    if (t <= 61) {
      asm volatile("s_waitcnt vmcnt(6)" ::: "memory");  // A(t+1),B(t) retired
    } else if (t == 62) {
      asm volatile("s_waitcnt vmcnt(4)" ::: "memory");  // A(63) retired
    }
    if (t < 63) __builtin_amdgcn_s_barrier();
    char* tmp = bR; bR = bN; bN = bS; bS = tmp;  // rotate A ring
  };

  for (int i = 0; i < 32; ++i) {  // tiles 0..63, banks alternate
    TILE(2 * i, bFa, bFb);
    TILE(2 * i + 1, bFb, bFa);
  }

  // epilogue: out = acc * sA[row]*scale[col] + bias[col]
  // 32x32 C/D layout: col = lane&31, row = (r&3) + 8*(r>>2) + 4*l32
  float sv[2], bv[2];
#pragma unroll
  for (int nb = 0; nb < 2; ++nb) {
    const int cc = bn + wc * 64 + nb * 32 + l31;
    sv[nb] = sc[cc];
    bv[nb] = bi[cc];
  }
#pragma unroll
  for (int mb = 0; mb < 4; ++mb) {
    const int rb = bm + wr * 128 + mb * 32 + l32 * 4;
    float sa[16];
#pragma unroll
    for (int r = 0; r < 16; ++r) sa[r] = sA[rb + (r & 3) + 8 * (r >> 2)];
#pragma unroll
    for (int nb = 0; nb < 2; ++nb) {
      const int cc = bn + wc * 64 + nb * 32 + l31;
#pragma unroll
      for (int r = 0; r < 16; ++r) {
        const long long row = rb + (r & 3) + 8 * (r >> 2);
        __builtin_nontemporal_store(
            (float)acc[mb][nb][r] * (sa[r] * sv[nb]) + bv[nb],
            out + row * NDIM + cc);
      }
    }
  }
}

// ---------- fallback: inline-convert reg-staged bf16 GEMM (if ws too small) ----
__global__ __launch_bounds__(256, 2) void gemm_inline(
    const float* __restrict__ A, const int* __restrict__ W,
    const float* __restrict__ sc, const float* __restrict__ bi,
    float* __restrict__ out) {
  typedef __bf16 bf16x8 __attribute__((ext_vector_type(8)));
  __shared__ unsigned short As[128 * 72];
  __shared__ unsigned short Bs[128 * 72];
  const int tid = threadIdx.x;
  const int lane = tid & 63;
  const int wv = tid >> 6;
  const int wg = (blockIdx.x & 7) * 1024 + (blockIdx.x >> 3);
  const int bm = (wg & 63) * 128;
  const int bn = (wg >> 6) * 128;
  const int wr = (wv >> 1) * 64;
  const int wc = (wv & 1) * 64;
  const int r16 = lane & 15;
  const int g4 = lane >> 4;

  f32x4 acc[4][4] = {};

  const int srow = tid >> 4;
  const int sc4 = (tid & 15) << 2;
  const float* aPtr = A + (long long)(bm + srow) * KDIM + sc4;
  const int* wPtr = W + (long long)(bn + srow) * KDIM + sc4;

  for (int kt = 0; kt < KDIM; kt += 64) {
    float4 av[8];
    int4 wv4[8];
#pragma unroll
    for (int j = 0; j < 8; ++j)
      av[j] = *(const float4*)(aPtr + (long long)j * 16 * KDIM + kt);
#pragma unroll
    for (int j = 0; j < 8; ++j)
      wv4[j] = *(const int4*)(wPtr + (long long)j * 16 * KDIM + kt);
    __syncthreads();
#pragma unroll
    for (int j = 0; j < 8; ++j) {
      ushort4 u;
      u.x = f2bf(av[j].x); u.y = f2bf(av[j].y);
      u.z = f2bf(av[j].z); u.w = f2bf(av[j].w);
      *(ushort4*)&As[(srow + j * 16) * 72 + sc4] = u;
    }
#pragma unroll
    for (int j = 0; j < 8; ++j) {
      ushort4 u;
      u.x = f2bf((float)wv4[j].x); u.y = f2bf((float)wv4[j].y);
      u.z = f2bf((float)wv4[j].z); u.w = f2bf((float)wv4[j].w);
      *(ushort4*)&Bs[(srow + j * 16) * 72 + sc4] = u;
    }
    __syncthreads();
#pragma unroll
    for (int ks = 0; ks < 2; ++ks) {
      bf16x8 aF[4], bF[4];
      const int kofs = ks * 32 + g4 * 8;
#pragma unroll
      for (int m2 = 0; m2 < 4; ++m2)
        aF[m2] = *(const bf16x8*)&As[(wr + m2 * 16 + r16) * 72 + kofs];
#pragma unroll
      for (int n2 = 0; n2 < 4; ++n2)
        bF[n2] = *(const bf16x8*)&Bs[(wc + n2 * 16 + r16) * 72 + kofs];
#pragma unroll
      for (int m2 = 0; m2 < 4; ++m2)
#pragma unroll
        for (int n2 = 0; n2 < 4; ++n2)
          acc[m2][n2] = __builtin_amdgcn_mfma_f32_16x16x32_bf16(
              aF[m2], bF[n2], acc[m2][n2], 0, 0, 0);
    }
  }

  float sv[4], bv[4];
#pragma unroll
  for (int n2 = 0; n2 < 4; ++n2) {
    const int c = bn + wc + n2 * 16 + r16;
    sv[n2] = sc[c];
    bv[n2] = bi[c];
  }
#pragma unroll
  for (int m2 = 0; m2 < 4; ++m2) {
    const int row0 = bm + wr + m2 * 16 + g4 * 4;
#pragma unroll
    for (int n2 = 0; n2 < 4; ++n2) {
      const int c = bn + wc + n2 * 16 + r16;
      float* op = out + (long long)row0 * NDIM + c;
#pragma unroll
      for (int r = 0; r < 4; ++r)
        op[(long long)r * NDIM] = acc[m2][n2][r] * sv[n2] + bv[n2];
    }
  }
}

extern "C" void kernel_launch(void* const* d_in, const int* in_sizes, int n_in,
                              void* d_out, int out_size, void* d_ws, size_t ws_size,
                              hipStream_t stream) {
  const float* A = (const float*)d_in[0];
  const int* W = (const int*)d_in[1];
  const float* sc = (const float*)d_in[2];
  const float* bi = (const float*)d_in[3];
  float* out = (float*)d_out;

  const size_t needA = (size_t)MDIM * KDIM;          // int8: 32 MB
  const size_t needW = (size_t)NDIM * KDIM;          // int8: 64 MB
  const size_t offS = needA + needW;                 // 96 MB
  const size_t need = offS + (size_t)MDIM * 4;       // + sA

  if (d_ws != nullptr && ws_size >= need) {
    signed char* Ab = (signed char*)d_ws;
    signed char* Wb = (signed char*)d_ws + needA;
    float* sA = (float*)((char*)d_ws + offS);
    cvt_a_q8<<<8192, 256, 0, stream>>>(A, Ab, sA);
    cvt_w_q8<<<4096, 256, 0, stream>>>(W, Wb);
    gemm_i8_v17<<<2048, 512, 0, stream>>>(Ab, Wb, sA, sc, bi, out);
  } else {
    gemm_inline<<<8192, 256, 0, stream>>>(A, W, sc, bi, out);
  }
}

// Round 18
// 644.965 us; speedup vs baseline: 1.1523x; 1.0738x over previous
//
#include <hip/hip_runtime.h>

#define MDIM 8192
#define NDIM 16384
#define KDIM 4096

typedef int i32x4 __attribute__((ext_vector_type(4)));
typedef int i32x16 __attribute__((ext_vector_type(16)));
typedef float f32x4 __attribute__((ext_vector_type(4)));

__device__ __forceinline__ unsigned short f2bf(float f) {
  __bf16 h = (__bf16)f;
  return __builtin_bit_cast(unsigned short, h);
}

__device__ __forceinline__ void gload_lds16(const void* g, void* l) {
  __builtin_amdgcn_global_load_lds(
      (const __attribute__((address_space(1))) unsigned int*)g,
      (__attribute__((address_space(3))) unsigned int*)l, 16, 0, 0);
}

// ======== int8 ws layouts (ks-plane-major, 16B cells) ======
// Ab: [mtile(32)][kt64(64)][ks(4)][row(256)][16]  -> 16KB per (mtile,kt)
// Wb: [ntile(64)][kt64(64)][ks(4)][row(256)][16]
// Every MFMA fragment = 32 lanes x 16B contiguous. sA: 8192 floats after Wb.

// ---------- pass 1a: dynamic per-row quantization A fp32 -> int8 ----------
__global__ __launch_bounds__(256) void cvt_a_q8(const float* __restrict__ a,
                                                signed char* __restrict__ o,
                                                float* __restrict__ sA) {
  const int row = blockIdx.x;  // 0..8191
  const int tid = threadIdx.x;
  float v[16];
  const float4* s4 = (const float4*)(a + (long long)row * KDIM + tid * 16);
#pragma unroll
  for (int i = 0; i < 4; ++i) {
    float4 f = s4[i];
    v[i * 4 + 0] = f.x; v[i * 4 + 1] = f.y;
    v[i * 4 + 2] = f.z; v[i * 4 + 3] = f.w;
  }
  float m = 0.f;
#pragma unroll
  for (int i = 0; i < 16; ++i) m = fmaxf(m, fabsf(v[i]));
#pragma unroll
  for (int off = 32; off; off >>= 1) m = fmaxf(m, __shfl_xor(m, off));
  __shared__ float red[4];
  if ((tid & 63) == 0) red[tid >> 6] = m;
  __syncthreads();
  m = fmaxf(fmaxf(red[0], red[1]), fmaxf(red[2], red[3]));
  const float inv = m > 0.f ? 127.f / m : 0.f;
  if (tid == 0) sA[row] = m * (1.f / 127.f);
  union { signed char c[16]; uint4 u; } p;
#pragma unroll
  for (int i = 0; i < 16; ++i)
    p.c[i] = (signed char)__float2int_rn(v[i] * inv);  // |v*inv| <= 127
  const int kt = tid >> 2, ks = tid & 3;
  *(uint4*)(o + ((((long long)(row >> 8) * 64 + kt) * 4 + ks) << 12) +
            ((row & 255) << 4)) = p.u;
}

// ---------- pass 1b: W int32 (int8 values, exact) -> int8 tile-panel --------
__global__ __launch_bounds__(256) void cvt_w_q8(const int* __restrict__ w,
                                                signed char* __restrict__ o) {
  const int nt = blockIdx.x >> 6;
  const int kt = blockIdx.x & 63;
  const int t = threadIdx.x;  // row (output channel within panel)
  const int* src = w + (long long)(nt * 256 + t) * KDIM + kt * 64;
  signed char* dst = o + (((long long)(nt * 64 + kt) * 4) << 12) + (t << 4);
#pragma unroll
  for (int ks = 0; ks < 4; ++ks) {
    union { signed char c[16]; uint4 u; } p;
#pragma unroll
    for (int i = 0; i < 4; ++i) {
      int4 x = *(const int4*)(src + ks * 16 + i * 4);
      p.c[i * 4 + 0] = (signed char)x.x; p.c[i * 4 + 1] = (signed char)x.y;
      p.c[i * 4 + 2] = (signed char)x.z; p.c[i * 4 + 3] = (signed char)x.w;
    }
    *(uint4*)(dst + (ks << 12)) = p.u;
  }
}

// ---------- pass 2: int8 GEMM, v13 geometry + m201 fine-phase cadence ----
// 256x256 tile, BK=64, 8 waves x (128x64), mfma_i32_32x32x32_i8,
// 3-slot ring (96 KiB), counted vmcnt(4). Per K-tile t, TWO phases:
//   ph1: [2 gl_lds piece A(t+2)] [6 C++ ds_reads kk0] barrier
//        setprio(1) 8 MFMA kk0 setprio(0) barrier
//   ph2: [2 gl_lds piece B(t+2)] [6 C++ ds_reads kk1] barrier
//        setprio(1) 8 MFMA kk1 setprio(0) [vmcnt(4)] barrier
// NO sched_barrier / asm lgkmcnt: compiler emits minimal per-dep lgkmcnt(N)
// (r7's pins were m141's order-pinning regression). Gate ledger: during t
// exactly 4 loads issue; vmcnt(4) at t's end retires everything older =>
// tile t+1 resident. WAR: stage(t+2) -> slot of t-1, freed at t-1's barrier.
// Tail: t=62 -> vmcnt(0) (tile 63's loads issued at t=61); t=63 -> none.
__global__ __launch_bounds__(512, 2) void gemm_i8_v18(
    const signed char* __restrict__ Ab, const signed char* __restrict__ Wb,
    const float* __restrict__ sA, const float* __restrict__ sc,
    const float* __restrict__ bi, float* __restrict__ out) {
  __shared__ alignas(16) char sm[3 * 32768];
  const int tid = threadIdx.x;
  const int lane = tid & 63;
  const int wv = tid >> 6;
  const int l31 = lane & 31;
  const int l32 = lane >> 5;
  const int wr = wv >> 2;   // 0..1 -> rows wr*128
  const int wc = wv & 3;    // 0..3 -> cols wc*64
  // 2D XCD chunking (verified: low FETCH)
  const int c = blockIdx.x & 7;
  const int l = blockIdx.x >> 3;              // 0..255
  const int mA = ((c & 3) << 3) + (l & 7);    // 0..31
  const int nT = ((c >> 2) << 5) + (l >> 3);  // 0..63
  const int bm = mA << 8;
  const int bn = nT << 8;

  int aO[2][4], bO[2][2];
#pragma unroll
  for (int kk = 0; kk < 2; ++kk) {
#pragma unroll
    for (int mb = 0; mb < 4; ++mb)
      aO[kk][mb] = (kk * 2 + l32) * 4096 + (wr * 128 + mb * 32 + l31) * 16;
#pragma unroll
    for (int nb = 0; nb < 2; ++nb)
      bO[kk][nb] = 16384 + (kk * 2 + l32) * 4096 + (wc * 64 + nb * 32 + l31) * 16;
  }

  i32x16 acc[4][2] = {};

  const signed char* aSrc = Ab + ((long long)mA << 20) + (tid << 4);
  const signed char* bSrc = Wb + ((long long)nT << 20) + (tid << 4);
  const int t16 = tid << 4;

  char* bR = &sm[0];
  char* bN = &sm[32768];
  char* bS = &sm[65536];

  auto STAGE_P1 = [&](char* slot) {  // piece A: A-halves of the K-tile
    gload_lds16(aSrc, slot + t16);
    gload_lds16(aSrc + 8192, slot + 8192 + t16);
  };
  auto STAGE_P2 = [&](char* slot) {  // piece B: B-halves; advance pointers
    gload_lds16(bSrc, slot + 16384 + t16);
    gload_lds16(bSrc + 8192, slot + 24576 + t16);
    aSrc += 16384;
    bSrc += 16384;
  };

  // prologue: tiles 0,1 staged; vmcnt(4) retires tile 0
  STAGE_P1(bR); STAGE_P2(bR);
  STAGE_P1(bN); STAGE_P2(bN);
  asm volatile("s_waitcnt vmcnt(4)" ::: "memory");
  __builtin_amdgcn_s_barrier();

  for (int t = 0; t < 64; ++t) {
    // ---------------- phase 1: kk=0 ----------------
    if (t <= 61) STAGE_P1(bS);
    i32x4 aF[4], bF[2];
#pragma unroll
    for (int mb = 0; mb < 4; ++mb) aF[mb] = *(const i32x4*)(bR + aO[0][mb]);
#pragma unroll
    for (int nb = 0; nb < 2; ++nb) bF[nb] = *(const i32x4*)(bR + bO[0][nb]);
    __builtin_amdgcn_s_barrier();
    __builtin_amdgcn_s_setprio(1);
#pragma unroll
    for (int mb = 0; mb < 4; ++mb)
#pragma unroll
      for (int nb = 0; nb < 2; ++nb)
        acc[mb][nb] = __builtin_amdgcn_mfma_i32_32x32x32_i8(
            aF[mb], bF[nb], acc[mb][nb], 0, 0, 0);
    __builtin_amdgcn_s_setprio(0);
    __builtin_amdgcn_s_barrier();

    // ---------------- phase 2: kk=1 ----------------
    if (t <= 61) STAGE_P2(bS);
#pragma unroll
    for (int mb = 0; mb < 4; ++mb) aF[mb] = *(const i32x4*)(bR + aO[1][mb]);
#pragma unroll
    for (int nb = 0; nb < 2; ++nb) bF[nb] = *(const i32x4*)(bR + bO[1][nb]);
    __builtin_amdgcn_s_barrier();
    __builtin_amdgcn_s_setprio(1);
#pragma unroll
    for (int mb = 0; mb < 4; ++mb)
#pragma unroll
      for (int nb = 0; nb < 2; ++nb)
        acc[mb][nb] = __builtin_amdgcn_mfma_i32_32x32x32_i8(
            aF[mb], bF[nb], acc[mb][nb], 0, 0, 0);
    __builtin_amdgcn_s_setprio(0);
    if (t <= 61) {
      asm volatile("s_waitcnt vmcnt(4)" ::: "memory");  // tile t+1 resident
    } else if (t == 62) {
      asm volatile("s_waitcnt vmcnt(0)" ::: "memory");  // tile 63 resident
    }
    if (t < 63) __builtin_amdgcn_s_barrier();
    char* tmp = bR; bR = bN; bN = bS; bS = tmp;
  }

  // epilogue: out = acc * sA[row]*scale[col] + bias[col]
  // 32x32 C/D layout: col = lane&31, row = (r&3) + 8*(r>>2) + 4*l32
  float sv[2], bv[2];
#pragma unroll
  for (int nb = 0; nb < 2; ++nb) {
    const int cc = bn + wc * 64 + nb * 32 + l31;
    sv[nb] = sc[cc];
    bv[nb] = bi[cc];
  }
#pragma unroll
  for (int mb = 0; mb < 4; ++mb) {
    const int rb = bm + wr * 128 + mb * 32 + l32 * 4;
    float sa[16];
#pragma unroll
    for (int r = 0; r < 16; ++r) sa[r] = sA[rb + (r & 3) + 8 * (r >> 2)];
#pragma unroll
    for (int nb = 0; nb < 2; ++nb) {
      const int cc = bn + wc * 64 + nb * 32 + l31;
#pragma unroll
      for (int r = 0; r < 16; ++r) {
        const long long row = rb + (r & 3) + 8 * (r >> 2);
        __builtin_nontemporal_store(
            (float)acc[mb][nb][r] * (sa[r] * sv[nb]) + bv[nb],
            out + row * NDIM + cc);
      }
    }
  }
}

// ---------- fallback: inline-convert reg-staged bf16 GEMM (if ws too small) ----
__global__ __launch_bounds__(256, 2) void gemm_inline(
    const float* __restrict__ A, const int* __restrict__ W,
    const float* __restrict__ sc, const float* __restrict__ bi,
    float* __restrict__ out) {
  typedef __bf16 bf16x8 __attribute__((ext_vector_type(8)));
  __shared__ unsigned short As[128 * 72];
  __shared__ unsigned short Bs[128 * 72];
  const int tid = threadIdx.x;
  const int lane = tid & 63;
  const int wv = tid >> 6;
  const int wg = (blockIdx.x & 7) * 1024 + (blockIdx.x >> 3);
  const int bm = (wg & 63) * 128;
  const int bn = (wg >> 6) * 128;
  const int wr = (wv >> 1) * 64;
  const int wc = (wv & 1) * 64;
  const int r16 = lane & 15;
  const int g4 = lane >> 4;

  f32x4 acc[4][4] = {};

  const int srow = tid >> 4;
  const int sc4 = (tid & 15) << 2;
  const float* aPtr = A + (long long)(bm + srow) * KDIM + sc4;
  const int* wPtr = W + (long long)(bn + srow) * KDIM + sc4;

  for (int kt = 0; kt < KDIM; kt += 64) {
    float4 av[8];
    int4 wv4[8];
#pragma unroll
    for (int j = 0; j < 8; ++j)
      av[j] = *(const float4*)(aPtr + (long long)j * 16 * KDIM + kt);
#pragma unroll
    for (int j = 0; j < 8; ++j)
      wv4[j] = *(const int4*)(wPtr + (long long)j * 16 * KDIM + kt);
    __syncthreads();
#pragma unroll
    for (int j = 0; j < 8; ++j) {
      ushort4 u;
      u.x = f2bf(av[j].x); u.y = f2bf(av[j].y);
      u.z = f2bf(av[j].z); u.w = f2bf(av[j].w);
      *(ushort4*)&As[(srow + j * 16) * 72 + sc4] = u;
    }
#pragma unroll
    for (int j = 0; j < 8; ++j) {
      ushort4 u;
      u.x = f2bf((float)wv4[j].x); u.y = f2bf((float)wv4[j].y);
      u.z = f2bf((float)wv4[j].z); u.w = f2bf((float)wv4[j].w);
      *(ushort4*)&Bs[(srow + j * 16) * 72 + sc4] = u;
    }
    __syncthreads();
#pragma unroll
    for (int ks = 0; ks < 2; ++ks) {
      bf16x8 aF[4], bF[4];
      const int kofs = ks * 32 + g4 * 8;
#pragma unroll
      for (int m2 = 0; m2 < 4; ++m2)
        aF[m2] = *(const bf16x8*)&As[(wr + m2 * 16 + r16) * 72 + kofs];
#pragma unroll
      for (int n2 = 0; n2 < 4; ++n2)
        bF[n2] = *(const bf16x8*)&Bs[(wc + n2 * 16 + r16) * 72 + kofs];
#pragma unroll
      for (int m2 = 0; m2 < 4; ++m2)
#pragma unroll
        for (int n2 = 0; n2 < 4; ++n2)
          acc[m2][n2] = __builtin_amdgcn_mfma_f32_16x16x32_bf16(
              aF[m2], bF[n2], acc[m2][n2], 0, 0, 0);
    }
  }

  float sv[4], bv[4];
#pragma unroll
  for (int n2 = 0; n2 < 4; ++n2) {
    const int c = bn + wc + n2 * 16 + r16;
    sv[n2] = sc[c];
    bv[n2] = bi[c];
  }
#pragma unroll
  for (int m2 = 0; m2 < 4; ++m2) {
    const int row0 = bm + wr + m2 * 16 + g4 * 4;
#pragma unroll
    for (int n2 = 0; n2 < 4; ++n2) {
      const int c = bn + wc + n2 * 16 + r16;
      float* op = out + (long long)row0 * NDIM + c;
#pragma unroll
      for (int r = 0; r < 4; ++r)
        op[(long long)r * NDIM] = acc[m2][n2][r] * sv[n2] + bv[n2];
    }
  }
}

extern "C" void kernel_launch(void* const* d_in, const int* in_sizes, int n_in,
                              void* d_out, int out_size, void* d_ws, size_t ws_size,
                              hipStream_t stream) {
  const float* A = (const float*)d_in[0];
  const int* W = (const int*)d_in[1];
  const float* sc = (const float*)d_in[2];
  const float* bi = (const float*)d_in[3];
  float* out = (float*)d_out;

  const size_t needA = (size_t)MDIM * KDIM;          // int8: 32 MB
  const size_t needW = (size_t)NDIM * KDIM;          // int8: 64 MB
  const size_t offS = needA + needW;                 // 96 MB
  const size_t need = offS + (size_t)MDIM * 4;       // + sA

  if (d_ws != nullptr && ws_size >= need) {
    signed char* Ab = (signed char*)d_ws;
    signed char* Wb = (signed char*)d_ws + needA;
    float* sA = (float*)((char*)d_ws + offS);
    cvt_a_q8<<<8192, 256, 0, stream>>>(A, Ab, sA);
    cvt_w_q8<<<4096, 256, 0, stream>>>(W, Wb);
    gemm_i8_v18<<<2048, 512, 0, stream>>>(Ab, Wb, sA, sc, bi, out);
  } else {
    gemm_inline<<<8192, 256, 0, stream>>>(A, W, sc, bi, out);
  }
}